// Round 2
// baseline (1262.312 us; speedup 1.0000x reference)
//
#include <hip/hip_runtime.h>
#include <math.h>

// SmallRIN forward, restructured:
//  - recurrence is elementwise in (b,d)  -> tiny sequential kernel, no syncs
//  - all S timesteps independent after that -> batched GEMM-like kernels
//  - logits = one big fp32 vector GEMM (no fp32 MFMA on CDNA4)

#define PHIF 1.6180339887498949f

constexpr int B = 8, S = 128, V = 32000, D = 256, N = 256, L = 2;
constexpr int TWO_D = 512;
constexpr int M = S * B; // 1024 rows, row index tb = t*B + b

// workspace layout (floats)
constexpr size_t OFF_XR   = 0;                                  // [M][D]
constexpr size_t OFF_XI   = OFF_XR   + (size_t)M * D;           // [M][D]
constexpr size_t OFF_XC   = OFF_XI   + (size_t)M * D;           // [M][D]
constexpr size_t OFF_CS   = OFF_XC   + (size_t)M * D;           // [M][N]
constexpr size_t OFF_SS   = OFF_CS   + (size_t)M * N;           // [M][N]
constexpr size_t OFF_RW   = OFF_SS   + (size_t)M * N;           // [L][N][D] 1/(1+|Wn|)
constexpr size_t OFF_IPWT = OFF_RW   + (size_t)L * N * D;       // [L][2D][D] ip_w transposed
constexpr size_t OFF_OPRT = OFF_IPWT + (size_t)L * TWO_D * D;   // [L][N][D]  opr transposed
constexpr size_t OFF_OPIT = OFF_OPRT + (size_t)L * N * D;       // [L][N][D]  opi transposed

// ---------------------------------------------------------------- prep
// RW = 1/(1+|Wn|); transpose ip_w -> [k][d], opr/opi -> [n][d]
__global__ void prep_kernel(const float* __restrict__ Wn,
                            const float* __restrict__ ip_w,
                            const float* __restrict__ opr,
                            const float* __restrict__ opi,
                            float* __restrict__ ws) {
    int i = blockIdx.x * blockDim.x + threadIdx.x;   // grid covers 262144
    if (i < L * N * D) {
        ws[OFF_RW + i] = 1.0f / (1.0f + fabsf(Wn[i]));
        int l = i >> 16;         // 65536 per layer
        int r = i & 65535;
        int n = r >> 8;
        int d = r & 255;
        ws[OFF_OPRT + i] = opr[(size_t)l * D * N + (size_t)d * N + n];
        ws[OFF_OPIT + i] = opi[(size_t)l * D * N + (size_t)d * N + n];
    }
    if (i < L * TWO_D * D) {
        int l = i >> 17;         // 131072 per layer
        int r = i & 131071;
        int k = r >> 8;
        int d = r & 255;
        ws[OFF_IPWT + i] = ip_w[(size_t)l * D * TWO_D + (size_t)d * TWO_D + k];
    }
}

// ---------------------------------------------------------------- recurrence
// h[t][b][d] depends only on h[t-1][b][d] -> one thread per (b,d)
__global__ void recur_kernel(const int* __restrict__ ids,
                             const float* __restrict__ emb,
                             float* __restrict__ ws) {
    int tid = blockIdx.x * blockDim.x + threadIdx.x;
    if (tid >= B * D) return;
    int b = tid >> 8;
    int d = tid & 255;
    float* XR = ws + OFF_XR;
    float* XI = ws + OFF_XI;
    float hr = 0.f, hi = 0.f;
    for (int t = 0; t < S; ++t) {
        int id = ids[b * S + t];
        const float* e = emb + (size_t)id * TWO_D;
        float w  = e[d];
        float bb = e[D + d];
        float wl = 1.0f + fabsf(w);
        float tphi = (float)t * PHIF;
        float thr = hr / wl + bb + tphi;   // match ref op order
        float thi = hi / wl + bb + tphi;
        float sr, cr, si, ci;
        sincosf(thr, &sr, &cr);
        sincosf(thi, &si, &ci);
        float nhr = cr * ci - sr * si;
        float nhi = cr * si + sr * ci;
        int row = t * B + b;
        XR[row * D + d] = nhr;
        XI[row * D + d] = nhi;
        hr = nhr; hi = nhi;
    }
}

// ---------------------------------------------------------------- xc GEMM
// XC[m][d] = sum_k cat(XR,XI)[m][k] * ip_w[l][d][k] + ip_b[l][d]
__global__ __launch_bounds__(256) void xc_kernel(const float* __restrict__ ipb,
                                                 int l,
                                                 float* __restrict__ ws) {
    __shared__ float xrow[8][TWO_D];  // 16 KB
    const float* XR = ws + OFF_XR;
    const float* XI = ws + OFF_XI;
    const float* WT = ws + OFF_IPWT + (size_t)l * TWO_D * D;
    float* XC = ws + OFF_XC;
    int m0 = blockIdx.x * 8;
    int tid = threadIdx.x;
    for (int j = 0; j < 16; ++j) {
        int idx = tid + j * 256;          // 0..4095
        int r = idx >> 9;
        int k = idx & 511;
        xrow[r][k] = (k < D) ? XR[(m0 + r) * D + k] : XI[(m0 + r) * D + (k - D)];
    }
    __syncthreads();
    int d = tid;
    float bias = ipb[l * D + d];
    float acc[8];
    #pragma unroll
    for (int r = 0; r < 8; ++r) acc[r] = bias;
    for (int k = 0; k < TWO_D; ++k) {
        float wv = WT[k * D + d];          // coalesced
        #pragma unroll
        for (int r = 0; r < 8; ++r) acc[r] = fmaf(xrow[r][k], wv, acc[r]);  // LDS broadcast
    }
    #pragma unroll
    for (int r = 0; r < 8; ++r) XC[(m0 + r) * D + d] = acc[r];
}

// ---------------------------------------------------------------- theta sums (hot)
// CS[tb][n] = sum_d cos(XC[tb][d]*RW[n][d] + Bn[n][d] + t*phi), SS likewise.
// One wave per (n, 8 consecutive tb); lane covers d = 4*lane..4*lane+3.
__global__ __launch_bounds__(256) void theta_kernel(const float* __restrict__ Bn,
                                                    int l,
                                                    float* __restrict__ ws) {
    const float* RW = ws + OFF_RW + (size_t)l * N * D;
    const float* BN = Bn + (size_t)l * N * D;
    const float* XC = ws + OFF_XC;
    float* CS = ws + OFF_CS;
    float* SS = ws + OFF_SS;
    int wid  = (blockIdx.x * blockDim.x + threadIdx.x) >> 6;  // 0..32767
    int lane = threadIdx.x & 63;
    int n = wid & (N - 1);
    int g = wid >> 8;            // 0..127  (tb group)
    int d0 = lane * 4;
    float4 rw4 = *(const float4*)(RW + n * D + d0);
    float4 bn4 = *(const float4*)(BN + n * D + d0);
    for (int u = 0; u < 8; ++u) {
        int tb = g * 8 + u;
        int t = tb >> 3;                    // tb = t*B + b, B = 8
        float tphi = (float)t * PHIF;
        float4 xc4 = *(const float4*)(XC + tb * D + d0);
        float accc = 0.f, accs = 0.f;
        float th, sv, cv;
        th = fmaf(xc4.x, rw4.x, bn4.x) + tphi; sincosf(th, &sv, &cv); accc += cv; accs += sv;
        th = fmaf(xc4.y, rw4.y, bn4.y) + tphi; sincosf(th, &sv, &cv); accc += cv; accs += sv;
        th = fmaf(xc4.z, rw4.z, bn4.z) + tphi; sincosf(th, &sv, &cv); accc += cv; accs += sv;
        th = fmaf(xc4.w, rw4.w, bn4.w) + tphi; sincosf(th, &sv, &cv); accc += cv; accs += sv;
        #pragma unroll
        for (int off = 32; off > 0; off >>= 1) {
            accc += __shfl_xor(accc, off, 64);
            accs += __shfl_xor(accs, off, 64);
        }
        if (lane == 0) {
            CS[tb * N + n] = accc;
            SS[tb * N + n] = accs;
        }
    }
}

// ---------------------------------------------------------------- residual update
// XR[m][d] += silu(sum_n CS[m][n]*opr[l][d][n]);  XI likewise with SS/opi
__global__ __launch_bounds__(256) void update_kernel(int l, float* __restrict__ ws) {
    __shared__ float csh[8][N];   // 8 KB
    __shared__ float ssh[8][N];   // 8 KB
    const float* CS = ws + OFF_CS;
    const float* SS = ws + OFF_SS;
    const float* WR = ws + OFF_OPRT + (size_t)l * N * D;
    const float* WI = ws + OFF_OPIT + (size_t)l * N * D;
    float* XR = ws + OFF_XR;
    float* XI = ws + OFF_XI;
    int m0 = blockIdx.x * 8;
    int tid = threadIdx.x;
    for (int j = 0; j < 8; ++j) {
        int idx = tid + j * 256;
        int r = idx >> 8;
        int n = idx & 255;
        csh[r][n] = CS[(m0 + r) * N + n];
        ssh[r][n] = SS[(m0 + r) * N + n];
    }
    __syncthreads();
    int d = tid;
    float accr[8] = {0,0,0,0,0,0,0,0};
    float acci[8] = {0,0,0,0,0,0,0,0};
    for (int n = 0; n < N; ++n) {
        float wr = WR[n * D + d];
        float wi = WI[n * D + d];
        #pragma unroll
        for (int r = 0; r < 8; ++r) {
            accr[r] = fmaf(csh[r][n], wr, accr[r]);
            acci[r] = fmaf(ssh[r][n], wi, acci[r]);
        }
    }
    #pragma unroll
    for (int r = 0; r < 8; ++r) {
        float vr = accr[r], vi = acci[r];
        float sgr = 1.0f / (1.0f + expf(-vr));
        float sgi = 1.0f / (1.0f + expf(-vi));
        XR[(m0 + r) * D + d] += vr * sgr;
        XI[(m0 + r) * D + d] += vi * sgi;
    }
}

// ---------------------------------------------------------------- logits GEMM (dominant)
// out[b][t][v] = sum_k cat(XR,XI)[tb][k] * out_w[v][k] + out_b[v]
// M=1024, N=32000, K=512 fp32 vector GEMM. BM=256 BN=64 BK=32, 256 thr,
// thread tile 8x8: per k-step 4 b128 LDS reads / 64 fma = 0.5 B/flop
// (matches 128 B/clk LDS vs 256 flop/clk VALU per CU).
constexpr int GBM = 256, GBN = 64, GBK = 32;
constexpr int LDA = GBM + 4;   // 260 floats: 16B-aligned rows, breaks pow2 bank stride
constexpr int LDW = GBN + 4;   // 68

__global__ __launch_bounds__(256) void logits_kernel(const float* __restrict__ out_w,
                                                     const float* __restrict__ out_b,
                                                     const float* __restrict__ ws,
                                                     float* __restrict__ out) {
    __shared__ float As[GBK][LDA];   // 33.3 KB
    __shared__ float Wsh[GBK][LDW];  // 8.7 KB
    const float* XR = ws + OFF_XR;
    const float* XI = ws + OFF_XI;
    int cb = blockIdx.x % (V / GBN);     // 500 col blocks
    int rb = blockIdx.x / (V / GBN);     // 4 row blocks
    int tid = threadIdx.x;
    int tx = tid & 7;        // 8 col groups
    int ty = tid >> 3;       // 32 row groups
    int m_base = ty * 8;
    int n0 = tx * 8;
    float acc[8][8];
    #pragma unroll
    for (int r = 0; r < 8; ++r)
        #pragma unroll
        for (int c = 0; c < 8; ++c) acc[r][c] = 0.f;

    for (int kc = 0; kc < TWO_D; kc += GBK) {
        #pragma unroll
        for (int j = 0; j < 32; ++j) {        // stage A: 256x32
            int idx = tid + j * 256;
            int k = idx & 31;
            int m = idx >> 5;
            int kg = kc + k;
            int row = rb * GBM + m;
            As[k][m] = (kg < D) ? XR[row * D + kg] : XI[row * D + (kg - D)];
        }
        #pragma unroll
        for (int j = 0; j < 8; ++j) {         // stage W: 64x32
            int idx = tid + j * 256;
            int k = idx & 31;
            int n = idx >> 5;
            Wsh[k][n] = out_w[(size_t)(cb * GBN + n) * TWO_D + kc + k];
        }
        __syncthreads();
        #pragma unroll 8
        for (int k = 0; k < GBK; ++k) {
            float4 a0 = *(const float4*)&As[k][m_base];
            float4 a1 = *(const float4*)&As[k][m_base + 4];
            float4 w0 = *(const float4*)&Wsh[k][n0];
            float4 w1 = *(const float4*)&Wsh[k][n0 + 4];
            float am[8] = {a0.x, a0.y, a0.z, a0.w, a1.x, a1.y, a1.z, a1.w};
            float wn[8] = {w0.x, w0.y, w0.z, w0.w, w1.x, w1.y, w1.z, w1.w};
            #pragma unroll
            for (int r = 0; r < 8; ++r)
                #pragma unroll
                for (int c = 0; c < 8; ++c)
                    acc[r][c] = fmaf(am[r], wn[c], acc[r][c]);
        }
        __syncthreads();
    }
    int v0 = cb * GBN + n0;
    float4 ob0 = *(const float4*)&out_b[v0];
    float4 ob1 = *(const float4*)&out_b[v0 + 4];
    float obn[8] = {ob0.x, ob0.y, ob0.z, ob0.w, ob1.x, ob1.y, ob1.z, ob1.w};
    #pragma unroll
    for (int r = 0; r < 8; ++r) {
        int row = rb * GBM + m_base + r;     // tb = t*B + b
        int t = row >> 3;
        int b = row & 7;
        float o[8];
        #pragma unroll
        for (int c = 0; c < 8; ++c) o[c] = acc[r][c] + obn[c];
        *(float4*)&out[((size_t)(b * S + t)) * V + v0]     = *(float4*)&o[0];
        *(float4*)&out[((size_t)(b * S + t)) * V + v0 + 4] = *(float4*)&o[4];
    }
}

// ---------------------------------------------------------------- launcher
extern "C" void kernel_launch(void* const* d_in, const int* in_sizes, int n_in,
                              void* d_out, int out_size, void* d_ws, size_t ws_size,
                              hipStream_t stream) {
    const int*   ids   = (const int*)d_in[0];
    const float* emb   = (const float*)d_in[1];
    const float* ip_w  = (const float*)d_in[2];
    const float* ip_b  = (const float*)d_in[3];
    const float* Wn    = (const float*)d_in[4];
    const float* Bn    = (const float*)d_in[5];
    const float* opr   = (const float*)d_in[6];
    const float* opi   = (const float*)d_in[7];
    const float* out_w = (const float*)d_in[8];
    const float* out_b = (const float*)d_in[9];
    float* out = (float*)d_out;
    float* ws  = (float*)d_ws;

    hipLaunchKernelGGL(prep_kernel,  dim3(1024), dim3(256), 0, stream, Wn, ip_w, opr, opi, ws);
    hipLaunchKernelGGL(recur_kernel, dim3(32),   dim3(64),  0, stream, ids, emb, ws);
    for (int l = 0; l < L; ++l) {
        hipLaunchKernelGGL(xc_kernel,     dim3(M / 8), dim3(256), 0, stream, ip_b, l, ws);
        hipLaunchKernelGGL(theta_kernel,  dim3(8192),  dim3(256), 0, stream, Bn, l, ws);
        hipLaunchKernelGGL(update_kernel, dim3(M / 8), dim3(256), 0, stream, l, ws);
    }
    hipLaunchKernelGGL(logits_kernel, dim3((V / GBN) * (M / GBM)), dim3(256), 0, stream,
                       out_w, out_b, ws, out);
}

// Round 6
// 721.768 us; speedup vs baseline: 1.7489x; 1.7489x over previous
//
#include <hip/hip_runtime.h>
#include <math.h>

// SmallRIN forward.
//  - recurrence factored out of the scan (elementwise in (b,d))
//  - per-layer resonant ops batched over all S*B rows
//  - logits GEMM on matrix cores: bf16 hi/lo split (AhWh + AhWl + AlWh),
//    m97-style 128x128 tile, global_load_lds staging. fp32 fallback if ws too small.

#define PHIF 1.6180339887498949f

typedef unsigned short u16;
typedef __attribute__((ext_vector_type(8))) short bf16x8;
typedef __attribute__((ext_vector_type(4))) float f32x4;

constexpr int B = 8, S = 128, V = 32000, D = 256, N = 256, L = 2;
constexpr int TWO_D = 512;
constexpr int M = S * B; // 1024 rows, row index tb = t*B + b

// workspace layout (float units for legacy part)
constexpr size_t OFF_XR   = 0;                                  // [M][D]
constexpr size_t OFF_XI   = OFF_XR   + (size_t)M * D;           // [M][D]
constexpr size_t OFF_XC   = OFF_XI   + (size_t)M * D;           // [M][D]
constexpr size_t OFF_CS   = OFF_XC   + (size_t)M * D;           // [M][N]
constexpr size_t OFF_SS   = OFF_CS   + (size_t)M * N;           // [M][N]
constexpr size_t OFF_RW   = OFF_SS   + (size_t)M * N;           // [L][N][D] 1/(1+|Wn|)
constexpr size_t OFF_IPWT = OFF_RW   + (size_t)L * N * D;       // [L][2D][D] ip_w^T
constexpr size_t OFF_OPRT = OFF_IPWT + (size_t)L * TWO_D * D;   // [L][N][D]  opr^T
constexpr size_t OFF_OPIT = OFF_OPRT + (size_t)L * N * D;       // [L][N][D]  opi^T
constexpr size_t OFF_FLT_END = OFF_OPIT + (size_t)L * N * D;    // 1,966,080 floats

// bf16 split buffers (byte offsets into ws)
constexpr size_t A2_BYTE_OFF = OFF_FLT_END * 4;                       // [M][1024] u16 = 2 MB
constexpr size_t W2_BYTE_OFF = A2_BYTE_OFF + (size_t)M * 1024 * 2;    // [V][1024] u16 = 65.5 MB
constexpr size_t WS_NEED     = W2_BYTE_OFF + (size_t)V * 1024 * 2;    // ~75.5 MB

__device__ __forceinline__ u16 f2bf(float x) {
    unsigned u = __float_as_uint(x);
    return (u16)((u + 0x7fffu + ((u >> 16) & 1u)) >> 16);   // RNE
}
__device__ __forceinline__ float bf2f(u16 h) {
    return __uint_as_float(((unsigned)h) << 16);
}

// ---------------------------------------------------------------- prep
__global__ void prep_kernel(const float* __restrict__ Wn,
                            const float* __restrict__ ip_w,
                            const float* __restrict__ opr,
                            const float* __restrict__ opi,
                            float* __restrict__ ws) {
    int i = blockIdx.x * blockDim.x + threadIdx.x;
    if (i < L * N * D) {
        ws[OFF_RW + i] = 1.0f / (1.0f + fabsf(Wn[i]));
        int l = i >> 16;
        int r = i & 65535;
        int n = r >> 8;
        int d = r & 255;
        ws[OFF_OPRT + i] = opr[(size_t)l * D * N + (size_t)d * N + n];
        ws[OFF_OPIT + i] = opi[(size_t)l * D * N + (size_t)d * N + n];
    }
    if (i < L * TWO_D * D) {
        int l = i >> 17;
        int r = i & 131071;
        int k = r >> 8;
        int d = r & 255;
        ws[OFF_IPWT + i] = ip_w[(size_t)l * D * TWO_D + (size_t)d * TWO_D + k];
    }
}

// ---------------------------------------------------------------- W split (per call)
__global__ __launch_bounds__(256) void conv_w_kernel(const float* __restrict__ out_w,
                                                     u16* __restrict__ W2) {
    int gid = blockIdx.x * blockDim.x + threadIdx.x;  // V*128 = 4,096,000
    if (gid >= V * 128) return;
    int v  = gid >> 7;
    int kq = (gid & 127) << 2;
    float4 x = *(const float4*)&out_w[(size_t)v * TWO_D + kq];
    u16 h0 = f2bf(x.x), h1 = f2bf(x.y), h2 = f2bf(x.z), h3 = f2bf(x.w);
    ushort4 hi = {h0, h1, h2, h3};
    ushort4 lo = {f2bf(x.x - bf2f(h0)), f2bf(x.y - bf2f(h1)),
                  f2bf(x.z - bf2f(h2)), f2bf(x.w - bf2f(h3))};
    *(ushort4*)&W2[(size_t)v * 1024 + kq]       = hi;
    *(ushort4*)&W2[(size_t)v * 1024 + 512 + kq] = lo;
}

// ---------------------------------------------------------------- A split (per call)
__global__ __launch_bounds__(256) void conv_a_kernel(const float* __restrict__ ws,
                                                     u16* __restrict__ A2) {
    int gid = blockIdx.x * blockDim.x + threadIdx.x;  // M*128 = 131072
    if (gid >= M * 128) return;
    int m  = gid >> 7;
    int kq = (gid & 127) << 2;
    const float* XR = ws + OFF_XR;
    const float* XI = ws + OFF_XI;
    float4 x = (kq < D) ? *(const float4*)&XR[(size_t)m * D + kq]
                        : *(const float4*)&XI[(size_t)m * D + kq - D];
    u16 h0 = f2bf(x.x), h1 = f2bf(x.y), h2 = f2bf(x.z), h3 = f2bf(x.w);
    ushort4 hi = {h0, h1, h2, h3};
    ushort4 lo = {f2bf(x.x - bf2f(h0)), f2bf(x.y - bf2f(h1)),
                  f2bf(x.z - bf2f(h2)), f2bf(x.w - bf2f(h3))};
    *(ushort4*)&A2[(size_t)m * 1024 + kq]       = hi;
    *(ushort4*)&A2[(size_t)m * 1024 + 512 + kq] = lo;
}

// ---------------------------------------------------------------- recurrence
__global__ void recur_kernel(const int* __restrict__ ids,
                             const float* __restrict__ emb,
                             float* __restrict__ ws) {
    int tid = blockIdx.x * blockDim.x + threadIdx.x;
    if (tid >= B * D) return;
    int b = tid >> 8;
    int d = tid & 255;
    float* XR = ws + OFF_XR;
    float* XI = ws + OFF_XI;
    float hr = 0.f, hi = 0.f;
    for (int t = 0; t < S; ++t) {
        int id = ids[b * S + t];
        const float* e = emb + (size_t)id * TWO_D;
        float w  = e[d];
        float bb = e[D + d];
        float wl = 1.0f + fabsf(w);
        float tphi = (float)t * PHIF;
        float thr = hr / wl + bb + tphi;
        float thi = hi / wl + bb + tphi;
        float sr, cr, si, ci;
        sincosf(thr, &sr, &cr);
        sincosf(thi, &si, &ci);
        float nhr = cr * ci - sr * si;
        float nhi = cr * si + sr * ci;
        int row = t * B + b;
        XR[row * D + d] = nhr;
        XI[row * D + d] = nhi;
        hr = nhr; hi = nhi;
    }
}

// ---------------------------------------------------------------- xc GEMM
__global__ __launch_bounds__(256) void xc_kernel(const float* __restrict__ ipb,
                                                 int l,
                                                 float* __restrict__ ws) {
    __shared__ float xrow[8][TWO_D];
    const float* XR = ws + OFF_XR;
    const float* XI = ws + OFF_XI;
    const float* WT = ws + OFF_IPWT + (size_t)l * TWO_D * D;
    float* XC = ws + OFF_XC;
    int m0 = blockIdx.x * 8;
    int tid = threadIdx.x;
    for (int j = 0; j < 16; ++j) {
        int idx = tid + j * 256;
        int r = idx >> 9;
        int k = idx & 511;
        xrow[r][k] = (k < D) ? XR[(m0 + r) * D + k] : XI[(m0 + r) * D + (k - D)];
    }
    __syncthreads();
    int d = tid;
    float bias = ipb[l * D + d];
    float acc[8];
    #pragma unroll
    for (int r = 0; r < 8; ++r) acc[r] = bias;
    for (int k = 0; k < TWO_D; ++k) {
        float wv = WT[k * D + d];
        #pragma unroll
        for (int r = 0; r < 8; ++r) acc[r] = fmaf(xrow[r][k], wv, acc[r]);
    }
    #pragma unroll
    for (int r = 0; r < 8; ++r) XC[(m0 + r) * D + d] = acc[r];
}

// ---------------------------------------------------------------- theta sums
__global__ __launch_bounds__(256) void theta_kernel(const float* __restrict__ Bn,
                                                    int l,
                                                    float* __restrict__ ws) {
    const float* RW = ws + OFF_RW + (size_t)l * N * D;
    const float* BN = Bn + (size_t)l * N * D;
    const float* XC = ws + OFF_XC;
    float* CS = ws + OFF_CS;
    float* SS = ws + OFF_SS;
    int wid  = (blockIdx.x * blockDim.x + threadIdx.x) >> 6;
    int lane = threadIdx.x & 63;
    int n = wid & (N - 1);
    int g = wid >> 8;
    int d0 = lane * 4;
    float4 rw4 = *(const float4*)(RW + n * D + d0);
    float4 bn4 = *(const float4*)(BN + n * D + d0);
    for (int u = 0; u < 8; ++u) {
        int tb = g * 8 + u;
        int t = tb >> 3;
        float tphi = (float)t * PHIF;
        float4 xc4 = *(const float4*)(XC + tb * D + d0);
        float accc = 0.f, accs = 0.f;
        float th, sv, cv;
        th = fmaf(xc4.x, rw4.x, bn4.x) + tphi; sincosf(th, &sv, &cv); accc += cv; accs += sv;
        th = fmaf(xc4.y, rw4.y, bn4.y) + tphi; sincosf(th, &sv, &cv); accc += cv; accs += sv;
        th = fmaf(xc4.z, rw4.z, bn4.z) + tphi; sincosf(th, &sv, &cv); accc += cv; accs += sv;
        th = fmaf(xc4.w, rw4.w, bn4.w) + tphi; sincosf(th, &sv, &cv); accc += cv; accs += sv;
        #pragma unroll
        for (int off = 32; off > 0; off >>= 1) {
            accc += __shfl_xor(accc, off, 64);
            accs += __shfl_xor(accs, off, 64);
        }
        if (lane == 0) {
            CS[tb * N + n] = accc;
            SS[tb * N + n] = accs;
        }
    }
}

// ---------------------------------------------------------------- residual update
__global__ __launch_bounds__(256) void update_kernel(int l, float* __restrict__ ws) {
    __shared__ float csh[8][N];
    __shared__ float ssh[8][N];
    const float* CS = ws + OFF_CS;
    const float* SS = ws + OFF_SS;
    const float* WR = ws + OFF_OPRT + (size_t)l * N * D;
    const float* WI = ws + OFF_OPIT + (size_t)l * N * D;
    float* XR = ws + OFF_XR;
    float* XI = ws + OFF_XI;
    int m0 = blockIdx.x * 8;
    int tid = threadIdx.x;
    for (int j = 0; j < 8; ++j) {
        int idx = tid + j * 256;
        int r = idx >> 8;
        int n = idx & 255;
        csh[r][n] = CS[(m0 + r) * N + n];
        ssh[r][n] = SS[(m0 + r) * N + n];
    }
    __syncthreads();
    int d = tid;
    float accr[8] = {0,0,0,0,0,0,0,0};
    float acci[8] = {0,0,0,0,0,0,0,0};
    for (int n = 0; n < N; ++n) {
        float wr = WR[n * D + d];
        float wi = WI[n * D + d];
        #pragma unroll
        for (int r = 0; r < 8; ++r) {
            accr[r] = fmaf(csh[r][n], wr, accr[r]);
            acci[r] = fmaf(ssh[r][n], wi, acci[r]);
        }
    }
    #pragma unroll
    for (int r = 0; r < 8; ++r) {
        float vr = accr[r], vi = acci[r];
        float sgr = 1.0f / (1.0f + expf(-vr));
        float sgi = 1.0f / (1.0f + expf(-vi));
        XR[(m0 + r) * D + d] += vr * sgr;
        XI[(m0 + r) * D + d] += vi * sgi;
    }
}

// ---------------------------------------------------------------- logits via MFMA
// C[m][v] = sum_k' A2seg[m][.] * W2seg[v][.] over effective K=1536:
//   kk in [0,512):    Ah x Wh      (aoff=kk,     woff=kk)
//   kk in [512,1024): Ah x Wl      (aoff=kk-512, woff=kk)
//   kk in [1024,1536):Al x Wh      (aoff=kk-512, woff=kk-1024)
// 128x128 tile, 4 waves (2x2), each wave 4x4 frags of 16x16x32.
__global__ __launch_bounds__(256) void logits_mfma_kernel(const u16* __restrict__ A2,
                                                          const u16* __restrict__ W2,
                                                          const float* __restrict__ out_b,
                                                          float* __restrict__ out) {
    __shared__ u16 sA[128 * 32];  // 8 KB, row-major [128][32]
    __shared__ u16 sW[128 * 32];  // 8 KB
    int cb = blockIdx.x % (V / 128);   // 250
    int rb = blockIdx.x / (V / 128);   // 8
    int tid = threadIdx.x;
    int w = tid >> 6, l = tid & 63;
    int wr = w >> 1, wc = w & 1;

    f32x4 acc[4][4];
    #pragma unroll
    for (int i = 0; i < 4; ++i)
        #pragma unroll
        for (int j = 0; j < 4; ++j) acc[i][j] = (f32x4){0.f, 0.f, 0.f, 0.f};

    int srow = l >> 2;          // 0..15
    int sko  = (l & 3) * 8;     // 0,8,16,24 (u16 units -> 16B)
    int kg = (l >> 4) * 8;      // frag k offset
    int rl = l & 15;            // frag row/col

    for (int kk = 0; kk < 1536; kk += 32) {
        int aoff = (kk < 512) ? kk : kk - 512;
        int woff = (kk < 1024) ? kk : kk - 1024;
        #pragma unroll
        for (int j = 0; j < 2; ++j) {
            int rloc = (w * 2 + j) * 16 + srow;
            const u16* sa = A2 + (size_t)(rb * 128 + rloc) * 1024 + aoff + sko;
            const u16* sw = W2 + (size_t)(cb * 128 + rloc) * 1024 + woff + sko;
            u16* da = &sA[rloc * 32 + sko];
            u16* dw = &sW[rloc * 32 + sko];
            __builtin_amdgcn_global_load_lds((const __attribute__((address_space(1))) void*)sa,
                                             (__attribute__((address_space(3))) void*)da, 16, 0, 0);
            __builtin_amdgcn_global_load_lds((const __attribute__((address_space(1))) void*)sw,
                                             (__attribute__((address_space(3))) void*)dw, 16, 0, 0);
        }
        __syncthreads();
        bf16x8 af[4], wf[4];
        #pragma unroll
        for (int f = 0; f < 4; ++f) {
            af[f] = *(const bf16x8*)&sA[(wr * 64 + f * 16 + rl) * 32 + kg];
            wf[f] = *(const bf16x8*)&sW[(wc * 64 + f * 16 + rl) * 32 + kg];
        }
        #pragma unroll
        for (int fr = 0; fr < 4; ++fr)
            #pragma unroll
            for (int fc = 0; fc < 4; ++fc)
                acc[fr][fc] = __builtin_amdgcn_mfma_f32_16x16x32_bf16(
                    af[fr], wf[fc], acc[fr][fc], 0, 0, 0);
        __syncthreads();
    }

    int rq = l >> 4;   // 0..3
    #pragma unroll
    for (int fc = 0; fc < 4; ++fc) {
        int v = cb * 128 + wc * 64 + fc * 16 + rl;
        float bv = out_b[v];
        #pragma unroll
        for (int fr = 0; fr < 4; ++fr) {
            #pragma unroll
            for (int r = 0; r < 4; ++r) {
                int row = rb * 128 + wr * 64 + fr * 16 + rq * 4 + r;  // tb = t*B + b
                int t = row >> 3, b = row & 7;
                out[((size_t)(b * S + t)) * V + v] = acc[fr][fc][r] + bv;
            }
        }
    }
}

// ---------------------------------------------------------------- fp32 fallback logits
constexpr int GBM = 256, GBN = 64, GBK = 32;
constexpr int LDA = GBM + 4;
constexpr int LDW = GBN + 4;

__global__ __launch_bounds__(256) void logits_kernel(const float* __restrict__ out_w,
                                                     const float* __restrict__ out_b,
                                                     const float* __restrict__ ws,
                                                     float* __restrict__ out) {
    __shared__ float As[GBK][LDA];
    __shared__ float Wsh[GBK][LDW];
    const float* XR = ws + OFF_XR;
    const float* XI = ws + OFF_XI;
    int cb = blockIdx.x % (V / GBN);
    int rb = blockIdx.x / (V / GBN);
    int tid = threadIdx.x;
    int tx = tid & 7;
    int ty = tid >> 3;
    int m_base = ty * 8;
    int n0 = tx * 8;
    float acc[8][8];
    #pragma unroll
    for (int r = 0; r < 8; ++r)
        #pragma unroll
        for (int c = 0; c < 8; ++c) acc[r][c] = 0.f;

    for (int kc = 0; kc < TWO_D; kc += GBK) {
        #pragma unroll
        for (int j = 0; j < 32; ++j) {
            int idx = tid + j * 256;
            int k = idx & 31;
            int m = idx >> 5;
            int kgl = kc + k;
            int row = rb * GBM + m;
            As[k][m] = (kgl < D) ? XR[row * D + kgl] : XI[row * D + (kgl - D)];
        }
        #pragma unroll
        for (int j = 0; j < 8; ++j) {
            int idx = tid + j * 256;
            int k = idx & 31;
            int n = idx >> 5;
            Wsh[k][n] = out_w[(size_t)(cb * GBN + n) * TWO_D + kc + k];
        }
        __syncthreads();
        #pragma unroll 8
        for (int k = 0; k < GBK; ++k) {
            float4 a0 = *(const float4*)&As[k][m_base];
            float4 a1 = *(const float4*)&As[k][m_base + 4];
            float4 w0 = *(const float4*)&Wsh[k][n0];
            float4 w1 = *(const float4*)&Wsh[k][n0 + 4];
            float am[8] = {a0.x, a0.y, a0.z, a0.w, a1.x, a1.y, a1.z, a1.w};
            float wn[8] = {w0.x, w0.y, w0.z, w0.w, w1.x, w1.y, w1.z, w1.w};
            #pragma unroll
            for (int r = 0; r < 8; ++r)
                #pragma unroll
                for (int c = 0; c < 8; ++c)
                    acc[r][c] = fmaf(am[r], wn[c], acc[r][c]);
        }
        __syncthreads();
    }
    int v0 = cb * GBN + n0;
    float4 ob0 = *(const float4*)&out_b[v0];
    float4 ob1 = *(const float4*)&out_b[v0 + 4];
    float obn[8] = {ob0.x, ob0.y, ob0.z, ob0.w, ob1.x, ob1.y, ob1.z, ob1.w};
    #pragma unroll
    for (int r = 0; r < 8; ++r) {
        int row = rb * GBM + m_base + r;
        int t = row >> 3;
        int b = row & 7;
        float o[8];
        #pragma unroll
        for (int c = 0; c < 8; ++c) o[c] = acc[r][c] + obn[c];
        *(float4*)&out[((size_t)(b * S + t)) * V + v0]     = *(float4*)&o[0];
        *(float4*)&out[((size_t)(b * S + t)) * V + v0 + 4] = *(float4*)&o[4];
    }
}

// ---------------------------------------------------------------- launcher
extern "C" void kernel_launch(void* const* d_in, const int* in_sizes, int n_in,
                              void* d_out, int out_size, void* d_ws, size_t ws_size,
                              hipStream_t stream) {
    const int*   ids   = (const int*)d_in[0];
    const float* emb   = (const float*)d_in[1];
    const float* ip_w  = (const float*)d_in[2];
    const float* ip_b  = (const float*)d_in[3];
    const float* Wn    = (const float*)d_in[4];
    const float* Bn    = (const float*)d_in[5];
    const float* opr   = (const float*)d_in[6];
    const float* opi   = (const float*)d_in[7];
    const float* out_w = (const float*)d_in[8];
    const float* out_b = (const float*)d_in[9];
    float* out = (float*)d_out;
    float* ws  = (float*)d_ws;
    const bool use_mfma = (ws_size >= WS_NEED);
    u16* A2 = (u16*)((char*)d_ws + A2_BYTE_OFF);
    u16* W2 = (u16*)((char*)d_ws + W2_BYTE_OFF);

    hipLaunchKernelGGL(prep_kernel,  dim3(1024), dim3(256), 0, stream, Wn, ip_w, opr, opi, ws);
    if (use_mfma)
        hipLaunchKernelGGL(conv_w_kernel, dim3(V * 128 / 256), dim3(256), 0, stream, out_w, W2);
    hipLaunchKernelGGL(recur_kernel, dim3(32),   dim3(64),  0, stream, ids, emb, ws);
    for (int l = 0; l < L; ++l) {
        hipLaunchKernelGGL(xc_kernel,     dim3(M / 8), dim3(256), 0, stream, ip_b, l, ws);
        hipLaunchKernelGGL(theta_kernel,  dim3(8192),  dim3(256), 0, stream, Bn, l, ws);
        hipLaunchKernelGGL(update_kernel, dim3(M / 8), dim3(256), 0, stream, l, ws);
    }
    if (use_mfma) {
        hipLaunchKernelGGL(conv_a_kernel, dim3(M * 128 / 256), dim3(256), 0, stream, ws, A2);
        hipLaunchKernelGGL(logits_mfma_kernel, dim3((V / 128) * (M / 128)), dim3(256), 0, stream,
                           A2, W2, out_b, out);
    } else {
        hipLaunchKernelGGL(logits_kernel, dim3((V / GBN) * (M / GBM)), dim3(256), 0, stream,
                           out_w, out_b, ws, out);
    }
}

// Round 7
// 585.070 us; speedup vs baseline: 2.1575x; 1.2336x over previous
//
#include <hip/hip_runtime.h>
#include <hip/hip_fp16.h>
#include <math.h>

// SmallRIN forward.
//  - recurrence factored out of the scan (elementwise in (b,d)), precise sincosf
//  - theta sums: transposed [d][n] layout, one lane per n, fast __sinf/__cosf, no shuffles
//  - logits GEMM on matrix cores: SINGLE fp16 (abs tol 0.5 >> fp16 error ~2e-3),
//    m97-style 128x128 tile, global_load_lds staging. fp32 fallback if ws too small.

#define PHIF 1.6180339887498949f

typedef unsigned short u16;
typedef __attribute__((ext_vector_type(8))) _Float16 f16x8;
typedef __attribute__((ext_vector_type(4))) float f32x4;

constexpr int B = 8, S = 128, V = 32000, D = 256, N = 256, L = 2;
constexpr int TWO_D = 512;
constexpr int M = S * B; // 1024 rows, row index tb = t*B + b

// workspace layout (float units)
constexpr size_t OFF_XR   = 0;                                  // [M][D]
constexpr size_t OFF_XI   = OFF_XR   + (size_t)M * D;           // [M][D]
constexpr size_t OFF_XC   = OFF_XI   + (size_t)M * D;           // [M][D]
constexpr size_t OFF_CS   = OFF_XC   + (size_t)M * D;           // [M][N]
constexpr size_t OFF_SS   = OFF_CS   + (size_t)M * N;           // [M][N]
constexpr size_t OFF_RWT  = OFF_SS   + (size_t)M * N;           // [L][D][N] 1/(1+|Wn|) transposed
constexpr size_t OFF_BNT  = OFF_RWT  + (size_t)L * N * D;       // [L][D][N] Bn transposed
constexpr size_t OFF_IPWT = OFF_BNT  + (size_t)L * N * D;       // [L][2D][D] ip_w^T
constexpr size_t OFF_OPRT = OFF_IPWT + (size_t)L * TWO_D * D;   // [L][N][D]  opr^T
constexpr size_t OFF_OPIT = OFF_OPRT + (size_t)L * N * D;       // [L][N][D]  opi^T
constexpr size_t OFF_FLT_END = OFF_OPIT + (size_t)L * N * D;    // 2,097,152 floats = 8 MB

// fp16 buffers (byte offsets into ws)
constexpr size_t A2_BYTE_OFF = OFF_FLT_END * 4;                       // [M][512] f16 = 1 MB
constexpr size_t W2_BYTE_OFF = A2_BYTE_OFF + (size_t)M * 512 * 2;     // [V][512] f16 = 32.8 MB
constexpr size_t WS_NEED     = W2_BYTE_OFF + (size_t)V * 512 * 2;     // ~41.8 MB

__device__ __forceinline__ u16 f2h(float x) {
    return __half_as_ushort(__float2half(x));   // RNE
}

// ---------------------------------------------------------------- prep
// Four transposes (write-coalesced, strided reads) + reciprocal.
__global__ void prep_kernel(const float* __restrict__ Wn,
                            const float* __restrict__ Bn,
                            const float* __restrict__ ip_w,
                            const float* __restrict__ opr,
                            const float* __restrict__ opi,
                            float* __restrict__ ws) {
    int i = blockIdx.x * blockDim.x + threadIdx.x;   // grid covers 262144
    if (i < L * N * D) {
        int l = i >> 16;
        int r = i & 65535;
        int a = r >> 8;          // slow index of the WRITE
        int c = r & 255;         // fast index of the WRITE (coalesced)
        // RWT[l][d=a][n=c] = 1/(1+|Wn[l][n=c][d=a]|);  BNT likewise
        float wv = Wn[(size_t)l * N * D + (size_t)c * D + a];
        ws[OFF_RWT + i] = 1.0f / (1.0f + fabsf(wv));
        ws[OFF_BNT + i] = Bn[(size_t)l * N * D + (size_t)c * D + a];
        // OPRT[l][n=a][d=c] = opr[l][d=c][n=a]
        ws[OFF_OPRT + i] = opr[(size_t)l * D * N + (size_t)c * N + a];
        ws[OFF_OPIT + i] = opi[(size_t)l * D * N + (size_t)c * N + a];
    }
    if (i < L * TWO_D * D) {
        int l = i >> 17;
        int r = i & 131071;
        int k = r >> 8;
        int d = r & 255;
        ws[OFF_IPWT + i] = ip_w[(size_t)l * D * TWO_D + (size_t)d * TWO_D + k];
    }
}

// ---------------------------------------------------------------- W -> fp16 (per call)
__global__ __launch_bounds__(256) void conv_w_kernel(const float* __restrict__ out_w,
                                                     u16* __restrict__ W2) {
    int gid = blockIdx.x * blockDim.x + threadIdx.x;  // V*128 = 4,096,000
    if (gid >= V * 128) return;
    int v  = gid >> 7;
    int kq = (gid & 127) << 2;
    float4 x = *(const float4*)&out_w[(size_t)v * TWO_D + kq];
    ushort4 h = {f2h(x.x), f2h(x.y), f2h(x.z), f2h(x.w)};
    *(ushort4*)&W2[(size_t)v * 512 + kq] = h;
}

// ---------------------------------------------------------------- A -> fp16 (per call)
__global__ __launch_bounds__(256) void conv_a_kernel(const float* __restrict__ ws,
                                                     u16* __restrict__ A2) {
    int gid = blockIdx.x * blockDim.x + threadIdx.x;  // M*128 = 131072
    if (gid >= M * 128) return;
    int m  = gid >> 7;
    int kq = (gid & 127) << 2;
    const float* XR = ws + OFF_XR;
    const float* XI = ws + OFF_XI;
    float4 x = (kq < D) ? *(const float4*)&XR[(size_t)m * D + kq]
                        : *(const float4*)&XI[(size_t)m * D + kq - D];
    ushort4 h = {f2h(x.x), f2h(x.y), f2h(x.z), f2h(x.w)};
    *(ushort4*)&A2[(size_t)m * 512 + kq] = h;
}

// ---------------------------------------------------------------- recurrence (precise)
__global__ void recur_kernel(const int* __restrict__ ids,
                             const float* __restrict__ emb,
                             float* __restrict__ ws) {
    int tid = blockIdx.x * blockDim.x + threadIdx.x;
    if (tid >= B * D) return;
    int b = tid >> 8;
    int d = tid & 255;
    float* XR = ws + OFF_XR;
    float* XI = ws + OFF_XI;
    float hr = 0.f, hi = 0.f;
    for (int t = 0; t < S; ++t) {
        int id = ids[b * S + t];
        const float* e = emb + (size_t)id * TWO_D;
        float w  = e[d];
        float bb = e[D + d];
        float wl = 1.0f + fabsf(w);
        float tphi = (float)t * PHIF;
        float thr = hr / wl + bb + tphi;
        float thi = hi / wl + bb + tphi;
        float sr, cr, si, ci;
        sincosf(thr, &sr, &cr);
        sincosf(thi, &si, &ci);
        float nhr = cr * ci - sr * si;
        float nhi = cr * si + sr * ci;
        int row = t * B + b;
        XR[row * D + d] = nhr;
        XI[row * D + d] = nhi;
        hr = nhr; hi = nhi;
    }
}

// ---------------------------------------------------------------- xc GEMM
__global__ __launch_bounds__(256) void xc_kernel(const float* __restrict__ ipb,
                                                 int l,
                                                 float* __restrict__ ws) {
    __shared__ float xrow[8][TWO_D];
    const float* XR = ws + OFF_XR;
    const float* XI = ws + OFF_XI;
    const float* WT = ws + OFF_IPWT + (size_t)l * TWO_D * D;
    float* XC = ws + OFF_XC;
    int m0 = blockIdx.x * 8;
    int tid = threadIdx.x;
    for (int j = 0; j < 16; ++j) {
        int idx = tid + j * 256;
        int r = idx >> 9;
        int k = idx & 511;
        xrow[r][k] = (k < D) ? XR[(m0 + r) * D + k] : XI[(m0 + r) * D + (k - D)];
    }
    __syncthreads();
    int d = tid;
    float bias = ipb[l * D + d];
    float acc[8];
    #pragma unroll
    for (int r = 0; r < 8; ++r) acc[r] = bias;
    for (int k = 0; k < TWO_D; ++k) {
        float wv = WT[k * D + d];
        #pragma unroll
        for (int r = 0; r < 8; ++r) acc[r] = fmaf(xrow[r][k], wv, acc[r]);
    }
    #pragma unroll
    for (int r = 0; r < 8; ++r) XC[(m0 + r) * D + d] = acc[r];
}

// ---------------------------------------------------------------- theta sums (hot)
// lane owns one n; loop over d with transposed RWT/BNT (coalesced); XC rows via
// LDS broadcast; fast __sinf/__cosf; zero cross-lane ops. 2 tb rows per block.
__global__ __launch_bounds__(256) void theta_kernel(int l, float* __restrict__ ws) {
    __shared__ float xls[2][D];
    const float* RWT = ws + OFF_RWT + (size_t)l * D * N;
    const float* BNT = ws + OFF_BNT + (size_t)l * D * N;
    const float* XC = ws + OFF_XC;
    float* CS = ws + OFF_CS;
    float* SS = ws + OFF_SS;
    int tb0 = blockIdx.x * 2;
    int n = threadIdx.x;
    xls[0][n] = XC[(size_t)tb0 * D + n];
    xls[1][n] = XC[(size_t)(tb0 + 1) * D + n];
    __syncthreads();
    float tp0 = (float)(tb0 >> 3) * PHIF;         // tb = t*B + b
    float tp1 = (float)((tb0 + 1) >> 3) * PHIF;
    float ac0 = 0.f, as0 = 0.f, ac1 = 0.f, as1 = 0.f;
    #pragma unroll 4
    for (int d = 0; d < D; ++d) {
        float rw = RWT[d * N + n];
        float bn = BNT[d * N + n];
        float th0 = fmaf(xls[0][d], rw, bn) + tp0;
        float th1 = fmaf(xls[1][d], rw, bn) + tp1;
        ac0 += __cosf(th0); as0 += __sinf(th0);
        ac1 += __cosf(th1); as1 += __sinf(th1);
    }
    CS[(size_t)tb0 * N + n] = ac0;
    SS[(size_t)tb0 * N + n] = as0;
    CS[(size_t)(tb0 + 1) * N + n] = ac1;
    SS[(size_t)(tb0 + 1) * N + n] = as1;
}

// ---------------------------------------------------------------- residual update
__global__ __launch_bounds__(256) void update_kernel(int l, float* __restrict__ ws) {
    __shared__ float csh[8][N];
    __shared__ float ssh[8][N];
    const float* CS = ws + OFF_CS;
    const float* SS = ws + OFF_SS;
    const float* WR = ws + OFF_OPRT + (size_t)l * N * D;
    const float* WI = ws + OFF_OPIT + (size_t)l * N * D;
    float* XR = ws + OFF_XR;
    float* XI = ws + OFF_XI;
    int m0 = blockIdx.x * 8;
    int tid = threadIdx.x;
    for (int j = 0; j < 8; ++j) {
        int idx = tid + j * 256;
        int r = idx >> 8;
        int n = idx & 255;
        csh[r][n] = CS[(m0 + r) * N + n];
        ssh[r][n] = SS[(m0 + r) * N + n];
    }
    __syncthreads();
    int d = tid;
    float accr[8] = {0,0,0,0,0,0,0,0};
    float acci[8] = {0,0,0,0,0,0,0,0};
    for (int n = 0; n < N; ++n) {
        float wr = WR[n * D + d];
        float wi = WI[n * D + d];
        #pragma unroll
        for (int r = 0; r < 8; ++r) {
            accr[r] = fmaf(csh[r][n], wr, accr[r]);
            acci[r] = fmaf(ssh[r][n], wi, acci[r]);
        }
    }
    #pragma unroll
    for (int r = 0; r < 8; ++r) {
        float vr = accr[r], vi = acci[r];
        float sgr = 1.0f / (1.0f + expf(-vr));
        float sgi = 1.0f / (1.0f + expf(-vi));
        XR[(m0 + r) * D + d] += vr * sgr;
        XI[(m0 + r) * D + d] += vi * sgi;
    }
}

// ---------------------------------------------------------------- logits via fp16 MFMA
// C[m][v] = sum_k A2[m][k]*W2[v][k], K=512. 128x128 tile, 4 waves (2x2),
// each wave 4x4 frags of 16x16x32_f16.
__global__ __launch_bounds__(256) void logits_mfma_kernel(const u16* __restrict__ A2,
                                                          const u16* __restrict__ W2,
                                                          const float* __restrict__ out_b,
                                                          float* __restrict__ out) {
    __shared__ u16 sA[128 * 32];  // 8 KB, row-major [128][32]
    __shared__ u16 sW[128 * 32];  // 8 KB
    int cb = blockIdx.x % (V / 128);   // 250
    int rb = blockIdx.x / (V / 128);   // 8
    int tid = threadIdx.x;
    int w = tid >> 6, l = tid & 63;
    int wr = w >> 1, wc = w & 1;

    f32x4 acc[4][4];
    #pragma unroll
    for (int i = 0; i < 4; ++i)
        #pragma unroll
        for (int j = 0; j < 4; ++j) acc[i][j] = (f32x4){0.f, 0.f, 0.f, 0.f};

    int srow = l >> 2;          // 0..15
    int sko  = (l & 3) * 8;     // 0,8,16,24 (u16 units -> 16B)
    int kg = (l >> 4) * 8;      // frag k offset
    int rl = l & 15;            // frag row/col

    for (int kk = 0; kk < 512; kk += 32) {
        #pragma unroll
        for (int j = 0; j < 2; ++j) {
            int rloc = (w * 2 + j) * 16 + srow;
            const u16* sa = A2 + (size_t)(rb * 128 + rloc) * 512 + kk + sko;
            const u16* sw = W2 + (size_t)(cb * 128 + rloc) * 512 + kk + sko;
            u16* da = &sA[rloc * 32 + sko];
            u16* dw = &sW[rloc * 32 + sko];
            __builtin_amdgcn_global_load_lds((const __attribute__((address_space(1))) void*)sa,
                                             (__attribute__((address_space(3))) void*)da, 16, 0, 0);
            __builtin_amdgcn_global_load_lds((const __attribute__((address_space(1))) void*)sw,
                                             (__attribute__((address_space(3))) void*)dw, 16, 0, 0);
        }
        __syncthreads();
        f16x8 af[4], wf[4];
        #pragma unroll
        for (int f = 0; f < 4; ++f) {
            af[f] = *(const f16x8*)&sA[(wr * 64 + f * 16 + rl) * 32 + kg];
            wf[f] = *(const f16x8*)&sW[(wc * 64 + f * 16 + rl) * 32 + kg];
        }
        #pragma unroll
        for (int fr = 0; fr < 4; ++fr)
            #pragma unroll
            for (int fc = 0; fc < 4; ++fc)
                acc[fr][fc] = __builtin_amdgcn_mfma_f32_16x16x32_f16(
                    af[fr], wf[fc], acc[fr][fc], 0, 0, 0);
        __syncthreads();
    }

    int rq = l >> 4;   // 0..3
    #pragma unroll
    for (int fc = 0; fc < 4; ++fc) {
        int v = cb * 128 + wc * 64 + fc * 16 + rl;
        float bv = out_b[v];
        #pragma unroll
        for (int fr = 0; fr < 4; ++fr) {
            #pragma unroll
            for (int r = 0; r < 4; ++r) {
                int row = rb * 128 + wr * 64 + fr * 16 + rq * 4 + r;  // tb = t*B + b
                int t = row >> 3, b = row & 7;
                out[((size_t)(b * S + t)) * V + v] = acc[fr][fc][r] + bv;
            }
        }
    }
}

// ---------------------------------------------------------------- fp32 fallback logits
constexpr int GBM = 256, GBN = 64, GBK = 32;
constexpr int LDA = GBM + 4;
constexpr int LDW = GBN + 4;

__global__ __launch_bounds__(256) void logits_kernel(const float* __restrict__ out_w,
                                                     const float* __restrict__ out_b,
                                                     const float* __restrict__ ws,
                                                     float* __restrict__ out) {
    __shared__ float As[GBK][LDA];
    __shared__ float Wsh[GBK][LDW];
    const float* XR = ws + OFF_XR;
    const float* XI = ws + OFF_XI;
    int cb = blockIdx.x % (V / GBN);
    int rb = blockIdx.x / (V / GBN);
    int tid = threadIdx.x;
    int tx = tid & 7;
    int ty = tid >> 3;
    int m_base = ty * 8;
    int n0 = tx * 8;
    float acc[8][8];
    #pragma unroll
    for (int r = 0; r < 8; ++r)
        #pragma unroll
        for (int c = 0; c < 8; ++c) acc[r][c] = 0.f;

    for (int kc = 0; kc < TWO_D; kc += GBK) {
        #pragma unroll
        for (int j = 0; j < 32; ++j) {
            int idx = tid + j * 256;
            int k = idx & 31;
            int m = idx >> 5;
            int kgl = kc + k;
            int row = rb * GBM + m;
            As[k][m] = (kgl < D) ? XR[row * D + kgl] : XI[row * D + (kgl - D)];
        }
        #pragma unroll
        for (int j = 0; j < 8; ++j) {
            int idx = tid + j * 256;
            int k = idx & 31;
            int n = idx >> 5;
            Wsh[k][n] = out_w[(size_t)(cb * GBN + n) * TWO_D + kc + k];
        }
        __syncthreads();
        #pragma unroll 8
        for (int k = 0; k < GBK; ++k) {
            float4 a0 = *(const float4*)&As[k][m_base];
            float4 a1 = *(const float4*)&As[k][m_base + 4];
            float4 w0 = *(const float4*)&Wsh[k][n0];
            float4 w1 = *(const float4*)&Wsh[k][n0 + 4];
            float am[8] = {a0.x, a0.y, a0.z, a0.w, a1.x, a1.y, a1.z, a1.w};
            float wn[8] = {w0.x, w0.y, w0.z, w0.w, w1.x, w1.y, w1.z, w1.w};
            #pragma unroll
            for (int r = 0; r < 8; ++r)
                #pragma unroll
                for (int c = 0; c < 8; ++c)
                    acc[r][c] = fmaf(am[r], wn[c], acc[r][c]);
        }
        __syncthreads();
    }
    int v0 = cb * GBN + n0;
    float4 ob0 = *(const float4*)&out_b[v0];
    float4 ob1 = *(const float4*)&out_b[v0 + 4];
    float obn[8] = {ob0.x, ob0.y, ob0.z, ob0.w, ob1.x, ob1.y, ob1.z, ob1.w};
    #pragma unroll
    for (int r = 0; r < 8; ++r) {
        int row = rb * GBM + m_base + r;
        int t = row >> 3;
        int b = row & 7;
        float o[8];
        #pragma unroll
        for (int c = 0; c < 8; ++c) o[c] = acc[r][c] + obn[c];
        *(float4*)&out[((size_t)(b * S + t)) * V + v0]     = *(float4*)&o[0];
        *(float4*)&out[((size_t)(b * S + t)) * V + v0 + 4] = *(float4*)&o[4];
    }
}

// ---------------------------------------------------------------- launcher
extern "C" void kernel_launch(void* const* d_in, const int* in_sizes, int n_in,
                              void* d_out, int out_size, void* d_ws, size_t ws_size,
                              hipStream_t stream) {
    const int*   ids   = (const int*)d_in[0];
    const float* emb   = (const float*)d_in[1];
    const float* ip_w  = (const float*)d_in[2];
    const float* ip_b  = (const float*)d_in[3];
    const float* Wn    = (const float*)d_in[4];
    const float* Bn    = (const float*)d_in[5];
    const float* opr   = (const float*)d_in[6];
    const float* opi   = (const float*)d_in[7];
    const float* out_w = (const float*)d_in[8];
    const float* out_b = (const float*)d_in[9];
    float* out = (float*)d_out;
    float* ws  = (float*)d_ws;
    const bool use_mfma = (ws_size >= WS_NEED);
    u16* A2 = (u16*)((char*)d_ws + A2_BYTE_OFF);
    u16* W2 = (u16*)((char*)d_ws + W2_BYTE_OFF);

    hipLaunchKernelGGL(prep_kernel,  dim3(1024), dim3(256), 0, stream, Wn, Bn, ip_w, opr, opi, ws);
    if (use_mfma)
        hipLaunchKernelGGL(conv_w_kernel, dim3(V * 128 / 256), dim3(256), 0, stream, out_w, W2);
    hipLaunchKernelGGL(recur_kernel, dim3(32),   dim3(64),  0, stream, ids, emb, ws);
    for (int l = 0; l < L; ++l) {
        hipLaunchKernelGGL(xc_kernel,     dim3(M / 8), dim3(256), 0, stream, ip_b, l, ws);
        hipLaunchKernelGGL(theta_kernel,  dim3(M / 2), dim3(256), 0, stream, l, ws);
        hipLaunchKernelGGL(update_kernel, dim3(M / 8), dim3(256), 0, stream, l, ws);
    }
    if (use_mfma) {
        hipLaunchKernelGGL(conv_a_kernel, dim3(M * 128 / 256), dim3(256), 0, stream, ws, A2);
        hipLaunchKernelGGL(logits_mfma_kernel, dim3((V / 128) * (M / 128)), dim3(256), 0, stream,
                           A2, W2, out_b, out);
    } else {
        hipLaunchKernelGGL(logits_kernel, dim3((V / GBN) * (M / GBM)), dim3(256), 0, stream,
                           out_w, out_b, ws, out);
    }
}

// Round 9
// 495.016 us; speedup vs baseline: 2.5500x; 1.1819x over previous
//
#include <hip/hip_runtime.h>
#include <hip/hip_fp16.h>
#include <math.h>

// SmallRIN forward.
//  - recurrence: trig identity collapses (h_r,h_i) -> scalar u chain, native sincos,
//    all loads staged to LDS before the chain (latency-bound -> ~5us)
//  - theta sums: transposed [d][n] layout, one lane per n, fast __sinf/__cosf
//  - logits GEMM: fp16 MFMA (tol 0.5 >> fp16 err ~2e-3), 128x128 tile,
//    rb-fast block order for W L2/L3 reuse. fp32 fallback if ws too small.

#define PHIF 1.6180339887498949f

typedef unsigned short u16;
typedef __attribute__((ext_vector_type(8))) _Float16 f16x8;
typedef __attribute__((ext_vector_type(4))) float f32x4;

constexpr int B = 8, S = 128, V = 32000, D = 256, N = 256, L = 2;
constexpr int TWO_D = 512;
constexpr int M = S * B; // 1024 rows, row index tb = t*B + b

// workspace layout (float units)
constexpr size_t OFF_XR   = 0;                                  // [M][D]
constexpr size_t OFF_XI   = OFF_XR   + (size_t)M * D;           // [M][D]
constexpr size_t OFF_XC   = OFF_XI   + (size_t)M * D;           // [M][D]
constexpr size_t OFF_CS   = OFF_XC   + (size_t)M * D;           // [M][N]
constexpr size_t OFF_SS   = OFF_CS   + (size_t)M * N;           // [M][N]
constexpr size_t OFF_RWT  = OFF_SS   + (size_t)M * N;           // [L][D][N] 1/(1+|Wn|) transposed
constexpr size_t OFF_BNT  = OFF_RWT  + (size_t)L * N * D;       // [L][D][N] Bn transposed
constexpr size_t OFF_IPWT = OFF_BNT  + (size_t)L * N * D;       // [L][2D][D] ip_w^T
constexpr size_t OFF_OPRT = OFF_IPWT + (size_t)L * TWO_D * D;   // [L][N][D]  opr^T
constexpr size_t OFF_OPIT = OFF_OPRT + (size_t)L * N * D;       // [L][N][D]  opi^T
constexpr size_t OFF_FLT_END = OFF_OPIT + (size_t)L * N * D;    // 2,097,152 floats = 8 MB

// fp16 buffers (byte offsets into ws)
constexpr size_t A2_BYTE_OFF = OFF_FLT_END * 4;                       // [M][512] f16 = 1 MB
constexpr size_t W2_BYTE_OFF = A2_BYTE_OFF + (size_t)M * 512 * 2;     // [V][512] f16 = 32.8 MB
constexpr size_t WS_NEED     = W2_BYTE_OFF + (size_t)V * 512 * 2;     // ~41.8 MB

__device__ __forceinline__ u16 f2h(float x) {
    return __half_as_ushort(__float2half(x));   // RNE
}

// ---------------------------------------------------------------- prep
__global__ void prep_kernel(const float* __restrict__ Wn,
                            const float* __restrict__ Bn,
                            const float* __restrict__ ip_w,
                            const float* __restrict__ opr,
                            const float* __restrict__ opi,
                            float* __restrict__ ws) {
    int i = blockIdx.x * blockDim.x + threadIdx.x;   // grid covers 262144
    if (i < L * N * D) {
        int l = i >> 16;
        int r = i & 65535;
        int a = r >> 8;          // slow index of the WRITE
        int c = r & 255;         // fast index of the WRITE (coalesced)
        float wv = Wn[(size_t)l * N * D + (size_t)c * D + a];
        ws[OFF_RWT + i] = 1.0f / (1.0f + fabsf(wv));
        ws[OFF_BNT + i] = Bn[(size_t)l * N * D + (size_t)c * D + a];
        ws[OFF_OPRT + i] = opr[(size_t)l * D * N + (size_t)c * N + a];
        ws[OFF_OPIT + i] = opi[(size_t)l * D * N + (size_t)c * N + a];
    }
    if (i < L * TWO_D * D) {
        int l = i >> 17;
        int r = i & 131071;
        int k = r >> 8;
        int d = r & 255;
        ws[OFF_IPWT + i] = ip_w[(size_t)l * D * TWO_D + (size_t)d * TWO_D + k];
    }
}

// ---------------------------------------------------------------- W -> fp16 (per call)
__global__ __launch_bounds__(256) void conv_w_kernel(const float* __restrict__ out_w,
                                                     u16* __restrict__ W2) {
    int gid = blockIdx.x * blockDim.x + threadIdx.x;  // V*128 = 4,096,000
    if (gid >= V * 128) return;
    int v  = gid >> 7;
    int kq = (gid & 127) << 2;
    float4 x = *(const float4*)&out_w[(size_t)v * TWO_D + kq];
    ushort4 h = {f2h(x.x), f2h(x.y), f2h(x.z), f2h(x.w)};
    *(ushort4*)&W2[(size_t)v * 512 + kq] = h;
}

// ---------------------------------------------------------------- A -> fp16 (per call)
__global__ __launch_bounds__(256) void conv_a_kernel(const float* __restrict__ ws,
                                                     u16* __restrict__ A2) {
    int gid = blockIdx.x * blockDim.x + threadIdx.x;  // M*128 = 131072
    if (gid >= M * 128) return;
    int m  = gid >> 7;
    int kq = (gid & 127) << 2;
    const float* XR = ws + OFF_XR;
    const float* XI = ws + OFF_XI;
    float4 x = (kq < D) ? *(const float4*)&XR[(size_t)m * D + kq]
                        : *(const float4*)&XI[(size_t)m * D + kq - D];
    ushort4 h = {f2h(x.x), f2h(x.y), f2h(x.z), f2h(x.w)};
    *(ushort4*)&A2[(size_t)m * 512 + kq] = h;
}

// ---------------------------------------------------------------- recurrence
// Identity: h_r' = cos(th_r+th_i), h_i' = sin(th_r+th_i);
//   th_r+th_i = (h_r+h_i)/wl + 2*b + 2*t*phi  -> scalar chain in u = h_r+h_i.
// All embedding slices staged to LDS first; chain is register/LDS only.
__global__ __launch_bounds__(64) void recur_kernel(const int* __restrict__ ids,
                                                   const float* __restrict__ emb,
                                                   float* __restrict__ ws) {
    __shared__ int   sid[S];
    __shared__ float swv[S][64];
    __shared__ float sbv[S][64];
    int lane = threadIdx.x;          // 0..63
    int blk  = blockIdx.x;           // 0..31
    int b  = blk >> 2;               // 4 blocks per batch row
    int d  = (blk & 3) * 64 + lane;
    sid[lane]      = ids[b * S + lane];
    sid[64 + lane] = ids[b * S + 64 + lane];
    __syncthreads();
    #pragma unroll 16
    for (int t = 0; t < S; ++t) {
        const float* e = emb + (size_t)sid[t] * TWO_D;
        swv[t][lane] = e[d];
        sbv[t][lane] = e[D + d];
    }
    __syncthreads();
    float* XR = ws + OFF_XR;
    float* XI = ws + OFF_XI;
    float u = 0.f;
    #pragma unroll 8
    for (int t = 0; t < S; ++t) {
        float wl = 1.0f + fabsf(swv[t][lane]);
        float c  = 2.0f * sbv[t][lane] + (2.0f * PHIF) * (float)t;
        float psi = __fdividef(u, wl) + c;
        float sn = __sinf(psi);
        float cs = __cosf(psi);
        size_t row = (size_t)(t * B + b) * D + d;
        XR[row] = cs;
        XI[row] = sn;
        u = cs + sn;
    }
}

// ---------------------------------------------------------------- xc GEMM
__global__ __launch_bounds__(256) void xc_kernel(const float* __restrict__ ipb,
                                                 int l,
                                                 float* __restrict__ ws) {
    __shared__ float xrow[8][TWO_D];
    const float* XR = ws + OFF_XR;
    const float* XI = ws + OFF_XI;
    const float* WT = ws + OFF_IPWT + (size_t)l * TWO_D * D;
    float* XC = ws + OFF_XC;
    int m0 = blockIdx.x * 8;
    int tid = threadIdx.x;
    for (int j = 0; j < 16; ++j) {
        int idx = tid + j * 256;
        int r = idx >> 9;
        int k = idx & 511;
        xrow[r][k] = (k < D) ? XR[(m0 + r) * D + k] : XI[(m0 + r) * D + (k - D)];
    }
    __syncthreads();
    int d = tid;
    float bias = ipb[l * D + d];
    float acc[8];
    #pragma unroll
    for (int r = 0; r < 8; ++r) acc[r] = bias;
    for (int k = 0; k < TWO_D; ++k) {
        float wv = WT[k * D + d];
        #pragma unroll
        for (int r = 0; r < 8; ++r) acc[r] = fmaf(xrow[r][k], wv, acc[r]);
    }
    #pragma unroll
    for (int r = 0; r < 8; ++r) XC[(m0 + r) * D + d] = acc[r];
}

// ---------------------------------------------------------------- theta sums (hot)
__global__ __launch_bounds__(256) void theta_kernel(int l, float* __restrict__ ws) {
    __shared__ float xls[2][D];
    const float* RWT = ws + OFF_RWT + (size_t)l * D * N;
    const float* BNT = ws + OFF_BNT + (size_t)l * D * N;
    const float* XC = ws + OFF_XC;
    float* CS = ws + OFF_CS;
    float* SS = ws + OFF_SS;
    int tb0 = blockIdx.x * 2;
    int n = threadIdx.x;
    xls[0][n] = XC[(size_t)tb0 * D + n];
    xls[1][n] = XC[(size_t)(tb0 + 1) * D + n];
    __syncthreads();
    float tp0 = (float)(tb0 >> 3) * PHIF;         // tb = t*B + b
    float tp1 = (float)((tb0 + 1) >> 3) * PHIF;
    float ac0 = 0.f, as0 = 0.f, ac1 = 0.f, as1 = 0.f;
    #pragma unroll 4
    for (int d = 0; d < D; ++d) {
        float rw = RWT[d * N + n];
        float bn = BNT[d * N + n];
        float th0 = fmaf(xls[0][d], rw, bn) + tp0;
        float th1 = fmaf(xls[1][d], rw, bn) + tp1;
        ac0 += __cosf(th0); as0 += __sinf(th0);
        ac1 += __cosf(th1); as1 += __sinf(th1);
    }
    CS[(size_t)tb0 * N + n] = ac0;
    SS[(size_t)tb0 * N + n] = as0;
    CS[(size_t)(tb0 + 1) * N + n] = ac1;
    SS[(size_t)(tb0 + 1) * N + n] = as1;
}

// ---------------------------------------------------------------- residual update
__global__ __launch_bounds__(256) void update_kernel(int l, float* __restrict__ ws) {
    __shared__ float csh[8][N];
    __shared__ float ssh[8][N];
    const float* CS = ws + OFF_CS;
    const float* SS = ws + OFF_SS;
    const float* WR = ws + OFF_OPRT + (size_t)l * N * D;
    const float* WI = ws + OFF_OPIT + (size_t)l * N * D;
    float* XR = ws + OFF_XR;
    float* XI = ws + OFF_XI;
    int m0 = blockIdx.x * 8;
    int tid = threadIdx.x;
    for (int j = 0; j < 8; ++j) {
        int idx = tid + j * 256;
        int r = idx >> 8;
        int n = idx & 255;
        csh[r][n] = CS[(m0 + r) * N + n];
        ssh[r][n] = SS[(m0 + r) * N + n];
    }
    __syncthreads();
    int d = tid;
    float accr[8] = {0,0,0,0,0,0,0,0};
    float acci[8] = {0,0,0,0,0,0,0,0};
    for (int n = 0; n < N; ++n) {
        float wr = WR[n * D + d];
        float wi = WI[n * D + d];
        #pragma unroll
        for (int r = 0; r < 8; ++r) {
            accr[r] = fmaf(csh[r][n], wr, accr[r]);
            acci[r] = fmaf(ssh[r][n], wi, acci[r]);
        }
    }
    #pragma unroll
    for (int r = 0; r < 8; ++r) {
        float vr = accr[r], vi = acci[r];
        float sgr = 1.0f / (1.0f + expf(-vr));
        float sgi = 1.0f / (1.0f + expf(-vi));
        XR[(m0 + r) * D + d] += vr * sgr;
        XI[(m0 + r) * D + d] += vi * sgi;
    }
}

// ---------------------------------------------------------------- logits via fp16 MFMA
// rb is the FAST block index: 8 consecutive blocks share one W 128-row tile
// -> W fetched from HBM ~once, re-served from L2/L3.
__global__ __launch_bounds__(256) void logits_mfma_kernel(const u16* __restrict__ A2,
                                                          const u16* __restrict__ W2,
                                                          const float* __restrict__ out_b,
                                                          float* __restrict__ out) {
    __shared__ u16 sA[128 * 32];  // 8 KB, row-major [128][32]
    __shared__ u16 sW[128 * 32];  // 8 KB
    int rb = blockIdx.x & 7;           // 8 row blocks (fast)
    int cb = blockIdx.x >> 3;          // 250 col blocks
    int tid = threadIdx.x;
    int w = tid >> 6, l = tid & 63;
    int wr = w >> 1, wc = w & 1;

    f32x4 acc[4][4];
    #pragma unroll
    for (int i = 0; i < 4; ++i)
        #pragma unroll
        for (int j = 0; j < 4; ++j) acc[i][j] = (f32x4){0.f, 0.f, 0.f, 0.f};

    int srow = l >> 2;          // 0..15
    int sko  = (l & 3) * 8;     // 0,8,16,24 (u16 units -> 16B)
    int kg = (l >> 4) * 8;      // frag k offset
    int rl = l & 15;            // frag row/col

    for (int kk = 0; kk < 512; kk += 32) {
        #pragma unroll
        for (int j = 0; j < 2; ++j) {
            int rloc = (w * 2 + j) * 16 + srow;
            const u16* sa = A2 + (size_t)(rb * 128 + rloc) * 512 + kk + sko;
            const u16* sw = W2 + (size_t)(cb * 128 + rloc) * 512 + kk + sko;
            u16* da = &sA[rloc * 32 + sko];
            u16* dw = &sW[rloc * 32 + sko];
            __builtin_amdgcn_global_load_lds((const __attribute__((address_space(1))) void*)sa,
                                             (__attribute__((address_space(3))) void*)da, 16, 0, 0);
            __builtin_amdgcn_global_load_lds((const __attribute__((address_space(1))) void*)sw,
                                             (__attribute__((address_space(3))) void*)dw, 16, 0, 0);
        }
        __syncthreads();
        f16x8 af[4], wf[4];
        #pragma unroll
        for (int f = 0; f < 4; ++f) {
            af[f] = *(const f16x8*)&sA[(wr * 64 + f * 16 + rl) * 32 + kg];
            wf[f] = *(const f16x8*)&sW[(wc * 64 + f * 16 + rl) * 32 + kg];
        }
        #pragma unroll
        for (int fr = 0; fr < 4; ++fr)
            #pragma unroll
            for (int fc = 0; fc < 4; ++fc)
                acc[fr][fc] = __builtin_amdgcn_mfma_f32_16x16x32_f16(
                    af[fr], wf[fc], acc[fr][fc], 0, 0, 0);
        __syncthreads();
    }

    int rq = l >> 4;   // 0..3
    #pragma unroll
    for (int fc = 0; fc < 4; ++fc) {
        int v = cb * 128 + wc * 64 + fc * 16 + rl;
        float bv = out_b[v];
        #pragma unroll
        for (int fr = 0; fr < 4; ++fr) {
            #pragma unroll
            for (int r = 0; r < 4; ++r) {
                int row = rb * 128 + wr * 64 + fr * 16 + rq * 4 + r;  // tb = t*B + b
                int t = row >> 3, b = row & 7;
                out[((size_t)(b * S + t)) * V + v] = acc[fr][fc][r] + bv;
            }
        }
    }
}

// ---------------------------------------------------------------- fp32 fallback logits
constexpr int GBM = 256, GBN = 64, GBK = 32;
constexpr int LDA = GBM + 4;
constexpr int LDW = GBN + 4;

__global__ __launch_bounds__(256) void logits_kernel(const float* __restrict__ out_w,
                                                     const float* __restrict__ out_b,
                                                     const float* __restrict__ ws,
                                                     float* __restrict__ out) {
    __shared__ float As[GBK][LDA];
    __shared__ float Wsh[GBK][LDW];
    const float* XR = ws + OFF_XR;
    const float* XI = ws + OFF_XI;
    int cb = blockIdx.x % (V / GBN);
    int rb = blockIdx.x / (V / GBN);
    int tid = threadIdx.x;
    int tx = tid & 7;
    int ty = tid >> 3;
    int m_base = ty * 8;
    int n0 = tx * 8;
    float acc[8][8];
    #pragma unroll
    for (int r = 0; r < 8; ++r)
        #pragma unroll
        for (int c = 0; c < 8; ++c) acc[r][c] = 0.f;

    for (int kc = 0; kc < TWO_D; kc += GBK) {
        #pragma unroll
        for (int j = 0; j < 32; ++j) {
            int idx = tid + j * 256;
            int k = idx & 31;
            int m = idx >> 5;
            int kgl = kc + k;
            int row = rb * GBM + m;
            As[k][m] = (kgl < D) ? XR[row * D + kgl] : XI[row * D + (kgl - D)];
        }
        #pragma unroll
        for (int j = 0; j < 8; ++j) {
            int idx = tid + j * 256;
            int k = idx & 31;
            int n = idx >> 5;
            Wsh[k][n] = out_w[(size_t)(cb * GBN + n) * TWO_D + kc + k];
        }
        __syncthreads();
        #pragma unroll 8
        for (int k = 0; k < GBK; ++k) {
            float4 a0 = *(const float4*)&As[k][m_base];
            float4 a1 = *(const float4*)&As[k][m_base + 4];
            float4 w0 = *(const float4*)&Wsh[k][n0];
            float4 w1 = *(const float4*)&Wsh[k][n0 + 4];
            float am[8] = {a0.x, a0.y, a0.z, a0.w, a1.x, a1.y, a1.z, a1.w};
            float wn[8] = {w0.x, w0.y, w0.z, w0.w, w1.x, w1.y, w1.z, w1.w};
            #pragma unroll
            for (int r = 0; r < 8; ++r)
                #pragma unroll
                for (int c = 0; c < 8; ++c)
                    acc[r][c] = fmaf(am[r], wn[c], acc[r][c]);
        }
        __syncthreads();
    }
    int v0 = cb * GBN + n0;
    float4 ob0 = *(const float4*)&out_b[v0];
    float4 ob1 = *(const float4*)&out_b[v0 + 4];
    float obn[8] = {ob0.x, ob0.y, ob0.z, ob0.w, ob1.x, ob1.y, ob1.z, ob1.w};
    #pragma unroll
    for (int r = 0; r < 8; ++r) {
        int row = rb * GBM + m_base + r;
        int t = row >> 3;
        int b = row & 7;
        float o[8];
        #pragma unroll
        for (int c = 0; c < 8; ++c) o[c] = acc[r][c] + obn[c];
        *(float4*)&out[((size_t)(b * S + t)) * V + v0]     = *(float4*)&o[0];
        *(float4*)&out[((size_t)(b * S + t)) * V + v0 + 4] = *(float4*)&o[4];
    }
}

// ---------------------------------------------------------------- launcher
extern "C" void kernel_launch(void* const* d_in, const int* in_sizes, int n_in,
                              void* d_out, int out_size, void* d_ws, size_t ws_size,
                              hipStream_t stream) {
    const int*   ids   = (const int*)d_in[0];
    const float* emb   = (const float*)d_in[1];
    const float* ip_w  = (const float*)d_in[2];
    const float* ip_b  = (const float*)d_in[3];
    const float* Wn    = (const float*)d_in[4];
    const float* Bn    = (const float*)d_in[5];
    const float* opr   = (const float*)d_in[6];
    const float* opi   = (const float*)d_in[7];
    const float* out_w = (const float*)d_in[8];
    const float* out_b = (const float*)d_in[9];
    float* out = (float*)d_out;
    float* ws  = (float*)d_ws;
    const bool use_mfma = (ws_size >= WS_NEED);
    u16* A2 = (u16*)((char*)d_ws + A2_BYTE_OFF);
    u16* W2 = (u16*)((char*)d_ws + W2_BYTE_OFF);

    hipLaunchKernelGGL(prep_kernel,  dim3(1024), dim3(256), 0, stream, Wn, Bn, ip_w, opr, opi, ws);
    if (use_mfma)
        hipLaunchKernelGGL(conv_w_kernel, dim3(V * 128 / 256), dim3(256), 0, stream, out_w, W2);
    hipLaunchKernelGGL(recur_kernel, dim3(32), dim3(64), 0, stream, ids, emb, ws);
    for (int l = 0; l < L; ++l) {
        hipLaunchKernelGGL(xc_kernel,     dim3(M / 8), dim3(256), 0, stream, ip_b, l, ws);
        hipLaunchKernelGGL(theta_kernel,  dim3(M / 2), dim3(256), 0, stream, l, ws);
        hipLaunchKernelGGL(update_kernel, dim3(M / 8), dim3(256), 0, stream, l, ws);
    }
    if (use_mfma) {
        hipLaunchKernelGGL(conv_a_kernel, dim3(M * 128 / 256), dim3(256), 0, stream, ws, A2);
        hipLaunchKernelGGL(logits_mfma_kernel, dim3((V / 128) * (M / 128)), dim3(256), 0, stream,
                           A2, W2, out_b, out);
    } else {
        hipLaunchKernelGGL(logits_kernel, dim3((V / GBN) * (M / GBM)), dim3(256), 0, stream,
                           out_w, out_b, ws, out);
    }
}